// Round 11
// baseline (41.958 us; speedup 1.0000x reference)
//
#include <hip/hip_runtime.h>

// SigmoidDVHLoss: per-(batch,label) mean of sigmoid((dose-thr)/0.1) for pred
// and target, then MSE over the 8x3 DVH entries.
//
// loss = mean_{b,k} ( (sum_{m==k}(sig_p - sig_t)) / count_k )^2
//
// R5 (confirmed): global f64 hot-line atomics were the ~70us pacer.
// R6: staged intra-chunk vmcnt waits neutral.
// R7 FAILED: per-block device-scope __threadfence (L2 writeback / block).
// R8: known-good re-established at 41.7us (~5.1 TB/s effective from L3).
// R9/R10: block-turnover hypothesis. 1024 blocks x 4 chunks each, 2-deep
//   register pipeline: issue chunk j+1's 12 loads, wait vmcnt(12) (counted,
//   never 0 mid-loop), compute chunk j. R9 failed to compile: macro-as-arg
//   needs one-level indirection (argument matching precedes expansion) —
//   fixed with *_X wrappers.

#define NB 8
#define NK 3
#define VPB (1 << 21)        // 128^3 voxels per batch
#define BLOCK 256
#define CHUNKS_P 128         // blocks per batch
#define NBLOCKS_P (NB * CHUNKS_P)        // 1024 blocks
#define VOX_PER_BLOCK (VPB / CHUNKS_P)   // 16384 voxels = 4096 float4
#define ITER_BYTES 16384u                // 1024 float4 per iteration chunk

#define LOG2E_X10 14.4269504088896341f   // 10 / ln(2)

typedef float v4f __attribute__((ext_vector_type(4)));
typedef int   v4i __attribute__((ext_vector_type(4)));

// ws layout: float diff[3][NBLOCKS_P] | int count[3][NBLOCKS_P]

__global__ __launch_bounds__(BLOCK, 4) void dvh_sum_kernel(
    const float* __restrict__ pred,
    const float* __restrict__ targ,
    const int*   __restrict__ mask,
    const float* __restrict__ ptv,
    float*       __restrict__ wsd,
    int*         __restrict__ wsc)
{
    const int bid   = blockIdx.x;
    const int batch = bid / CHUNKS_P;
    const int chunk = bid % CHUNKS_P;
    const long base = (long)batch * VPB + (long)chunk * VOX_PER_BLOCK;

    const float* predb = pred + base;   // uniform -> SGPR pair
    const float* targb = targ + base;
    const int*   maskb = mask + base;

    const int tid = threadIdx.x;
    const unsigned off0 = (unsigned)(tid) * 16u;
    const unsigned off1 = (unsigned)(tid + BLOCK) * 16u;
    const unsigned off2 = (unsigned)(tid + 2 * BLOCK) * 16u;
    const unsigned off3 = (unsigned)(tid + 3 * BLOCK) * 16u;

    // per-iteration byte offsets (iteration j covers bytes [j*16384, ...))
    const unsigned o00 = off0,                 o01 = off1,                 o02 = off2,                 o03 = off3;
    const unsigned o10 = off0 + ITER_BYTES,    o11 = off1 + ITER_BYTES,    o12 = off2 + ITER_BYTES,    o13 = off3 + ITER_BYTES;
    const unsigned o20 = off0 + 2*ITER_BYTES,  o21 = off1 + 2*ITER_BYTES,  o22 = off2 + 2*ITER_BYTES,  o23 = off3 + 2*ITER_BYTES;
    const unsigned o30 = off0 + 3*ITER_BYTES,  o31 = off1 + 3*ITER_BYTES,  o32 = off2 + 3*ITER_BYTES,  o33 = off3 + 3*ITER_BYTES;

    v4f AP0, AP1, AP2, AP3, AT0, AT1, AT2, AT3;
    v4i AM0, AM1, AM2, AM3;
    v4f BP0, BP1, BP2, BP3, BT0, BT1, BT2, BT3;
    v4i BM0, BM1, BM2, BM3;

    // issue 12 loads for one chunk, no wait (16-param base macro)
    #define ISSUE12(P0,P1,P2,P3,T0,T1,T2,T3,M0,M1,M2,M3, q0,q1,q2,q3)    \
        asm volatile(                                                    \
            "global_load_dwordx4 %0,  %12, %16\n\t"                      \
            "global_load_dwordx4 %1,  %13, %16\n\t"                      \
            "global_load_dwordx4 %2,  %14, %16\n\t"                      \
            "global_load_dwordx4 %3,  %15, %16\n\t"                      \
            "global_load_dwordx4 %4,  %12, %17\n\t"                      \
            "global_load_dwordx4 %5,  %13, %17\n\t"                      \
            "global_load_dwordx4 %6,  %14, %17\n\t"                      \
            "global_load_dwordx4 %7,  %15, %17\n\t"                      \
            "global_load_dwordx4 %8,  %12, %18\n\t"                      \
            "global_load_dwordx4 %9,  %13, %18\n\t"                      \
            "global_load_dwordx4 %10, %14, %18\n\t"                      \
            "global_load_dwordx4 %11, %15, %18"                          \
            : "=&v"(P0), "=&v"(P1), "=&v"(P2), "=&v"(P3),                \
              "=&v"(T0), "=&v"(T1), "=&v"(T2), "=&v"(T3),                \
              "=&v"(M0), "=&v"(M1), "=&v"(M2), "=&v"(M3)                 \
            : "v"(q0), "v"(q1), "v"(q2), "v"(q3),                        \
              "s"(predb), "s"(targb), "s"(maskb));

    // counted wait; consumers are data-dependent on the "+v" ties
    #define WAIT12(N, P0,P1,P2,P3,T0,T1,T2,T3,M0,M1,M2,M3)               \
        asm volatile("s_waitcnt vmcnt(" #N ")"                           \
            : "+v"(P0), "+v"(P1), "+v"(P2), "+v"(P3),                    \
              "+v"(T0), "+v"(T1), "+v"(T2), "+v"(T3),                    \
              "+v"(M0), "+v"(M1), "+v"(M2), "+v"(M3));

    // scaled thresholds: sig = rcp(1 + 2^(thr*C - d*C))
    const float tc0 = ptv[0] * LOG2E_X10;
    const float tc1 = ptv[1] * LOG2E_X10;
    const float tc2 = ptv[2] * LOG2E_X10;

    float d0 = 0.f, d1 = 0.f, d2 = 0.f;   // sum of (sig_p - sig_t) per label
    int   c0 = 0,   c1 = 0,   c2 = 0;     // counts per label

    #define DO_ELEM(PJ, TJ, MJ)                                          \
    {                                                                    \
        const int mm = (MJ);                                             \
        const bool is1 = (mm == 1), is2 = (mm == 2), is3 = (mm == 3);    \
        const float thrC = is1 ? tc0 : (is2 ? tc1 : tc2);                \
        const float ep = __builtin_amdgcn_exp2f(                         \
                             __builtin_fmaf((PJ), -LOG2E_X10, thrC));    \
        const float et = __builtin_amdgcn_exp2f(                         \
                             __builtin_fmaf((TJ), -LOG2E_X10, thrC));    \
        const float sgp = __builtin_amdgcn_rcpf(1.0f + ep);              \
        const float sgt = __builtin_amdgcn_rcpf(1.0f + et);              \
        const float df  = sgp - sgt;                                     \
        d0 += is1 ? df : 0.0f;                                           \
        d1 += is2 ? df : 0.0f;                                           \
        d2 += is3 ? df : 0.0f;                                           \
        c0 += is1 ? 1 : 0;                                               \
        c1 += is2 ? 1 : 0;                                               \
        c2 += is3 ? 1 : 0;                                               \
    }

    #define DO_VEC4(P, T, M)                                             \
        DO_ELEM(P[0], T[0], M[0])                                        \
        DO_ELEM(P[1], T[1], M[1])                                        \
        DO_ELEM(P[2], T[2], M[2])                                        \
        DO_ELEM(P[3], T[3], M[3])

    #define DO_SET(P0,P1,P2,P3,T0,T1,T2,T3,M0,M1,M2,M3)                  \
        DO_VEC4(P0, T0, M0)                                              \
        DO_VEC4(P1, T1, M1)                                              \
        DO_VEC4(P2, T2, M2)                                              \
        DO_VEC4(P3, T3, M3)

    // one-level indirection: SET expands (12 names) during substitution,
    // THEN the 16-param base macro is matched on the rescanned body.
    #define ISSUE12_X(SET, q0,q1,q2,q3) ISSUE12(SET, q0, q1, q2, q3)
    #define WAIT12_X(N, SET)            WAIT12(N, SET)
    #define DO_SET_X(SET)               DO_SET(SET)

    #define SET_A AP0,AP1,AP2,AP3,AT0,AT1,AT2,AT3,AM0,AM1,AM2,AM3
    #define SET_B BP0,BP1,BP2,BP3,BT0,BT1,BT2,BT3,BM0,BM1,BM2,BM3

    // ---- 2-deep pipeline over 4 chunks ----
    ISSUE12_X(SET_A, o00, o01, o02, o03)        // chunk 0
    ISSUE12_X(SET_B, o10, o11, o12, o13)        // chunk 1
    WAIT12_X(12, SET_A)                         // chunk 0 ready, 1 in flight
    DO_SET_X(SET_A)
    ISSUE12_X(SET_A, o20, o21, o22, o23)        // chunk 2
    WAIT12_X(12, SET_B)                         // chunk 1 ready, 2 in flight
    DO_SET_X(SET_B)
    ISSUE12_X(SET_B, o30, o31, o32, o33)        // chunk 3
    WAIT12_X(12, SET_A)                         // chunk 2 ready, 3 in flight
    DO_SET_X(SET_A)
    WAIT12_X(0, SET_B)                          // chunk 3 ready
    DO_SET_X(SET_B)

    #undef SET_A
    #undef SET_B
    #undef DO_SET_X
    #undef WAIT12_X
    #undef ISSUE12_X
    #undef DO_SET
    #undef DO_VEC4
    #undef DO_ELEM
    #undef WAIT12
    #undef ISSUE12

    // wave(64) butterfly reduce: f32 for diffs, int for counts
    #pragma unroll
    for (int off = 32; off > 0; off >>= 1) {
        d0 += __shfl_down(d0, off, 64);
        d1 += __shfl_down(d1, off, 64);
        d2 += __shfl_down(d2, off, 64);
        c0 += __shfl_down(c0, off, 64);
        c1 += __shfl_down(c1, off, 64);
        c2 += __shfl_down(c2, off, 64);
    }

    __shared__ float redd[BLOCK / 64][3];
    __shared__ int   redc[BLOCK / 64][3];
    const int wid  = threadIdx.x >> 6;
    const int lane = threadIdx.x & 63;
    if (lane == 0) {
        redd[wid][0] = d0; redd[wid][1] = d1; redd[wid][2] = d2;
        redc[wid][0] = c0; redc[wid][1] = c1; redc[wid][2] = c2;
    }
    __syncthreads();

    if (tid < 6) {
        const int q = tid;                   // 0..2 diff, 3..5 count
        if (q < 3)
            wsd[(size_t)q * NBLOCKS_P + bid] =
                redd[0][q] + redd[1][q] + redd[2][q] + redd[3][q];
        else
            wsc[(size_t)(q - 3) * NBLOCKS_P + bid] =
                redc[0][q - 3] + redc[1][q - 3] + redc[2][q - 3] + redc[3][q - 3];
    }
}

// Single block: reduce all 24 (b,k) pairs and emit the scalar loss.
__global__ __launch_bounds__(256) void dvh_finalize_kernel(
    const float* __restrict__ wsd,
    const int*   __restrict__ wsc,
    float*       __restrict__ out)
{
    const int tid  = threadIdx.x;
    const int wave = tid >> 6;
    const int lane = tid & 63;

    __shared__ double lds[NB * NK];

    for (int j = wave; j < NB * NK; j += 4) {        // 6 pairs per wave
        const int b = j / NK, k = j % NK;
        const float* dp = wsd + (size_t)k * NBLOCKS_P + b * CHUNKS_P;
        const int*   cp = wsc + (size_t)k * NBLOCKS_P + b * CHUNKS_P;

        double sd = 0.0;
        int    sc = 0;
        #pragma unroll
        for (int i = lane; i < CHUNKS_P; i += 64) {  // 2 elems each
            sd += (double)dp[i];
            sc += cp[i];
        }
        #pragma unroll
        for (int off = 32; off > 0; off >>= 1) {
            sd += __shfl_down(sd, off, 64);
            sc += __shfl_down(sc, off, 64);
        }
        if (lane == 0) {
            const double d = sd / (double)sc;
            lds[j] = d * d;
        }
    }
    __syncthreads();

    if (tid == 0) {
        double t = 0.0;
        #pragma unroll
        for (int j = 0; j < NB * NK; ++j) t += lds[j];
        out[0] = (float)(t / (double)(NB * NK));
    }
}

extern "C" void kernel_launch(void* const* d_in, const int* in_sizes, int n_in,
                              void* d_out, int out_size, void* d_ws, size_t ws_size,
                              hipStream_t stream) {
    const float* pred = (const float*)d_in[0];
    const float* targ = (const float*)d_in[1];
    const int*   mask = (const int*)d_in[2];
    const float* ptv  = (const float*)d_in[3];
    float* out = (float*)d_out;

    float* wsd = (float*)d_ws;                   // 3 * 1024 floats
    int*   wsc = (int*)(wsd + 3 * NBLOCKS_P);    // 3 * 1024 ints

    dvh_sum_kernel<<<NBLOCKS_P, BLOCK, 0, stream>>>(pred, targ, mask, ptv, wsd, wsc);
    dvh_finalize_kernel<<<1, 256, 0, stream>>>(wsd, wsc, out);
}